// Round 13
// baseline (288.421 us; speedup 1.0000x reference)
//
#include <hip/hip_runtime.h>
#include <hip/hip_bf16.h>
#include <math.h>

// Problem constants (from reference)
#define BB 256
#define NN 256
#define NT (BB*NN)        // 65536 nodes per side
#define NT2 (2*NT)        // unified graph: both sides, side-1 ids offset by NT
#define NE (NT*16)        // 1048576 directed edges per side
#define DD 32
#define F1C 128
#define F2C 64
#define F3C 64
#define TT 16
#define BINS 16

// CSR bucket build (unified graph)
#define NBUCK 256
#define BSHIFT 9
#define BNODES 512
#define BCAP 10240
#define EPB 4096

typedef __attribute__((ext_vector_type(8))) short short8;   // 8 bf16 in 4 VGPRs
typedef __attribute__((ext_vector_type(4))) float f32x4;    // MFMA accumulator
typedef __attribute__((ext_vector_type(2))) float f32x2;

__device__ inline float b2f(ushort u) { return __uint_as_float(((uint)u) << 16); }
__device__ inline ushort f2b(float f) {
    uint u = __float_as_uint(f);
    return (ushort)((u + 0x7fffu + ((u >> 16) & 1u)) >> 16);
}
// fp8 e4m3 helpers (clamp to +-448 so saturation can never produce NaN)
__device__ inline float clamp8(float v) { return fminf(fmaxf(v, -448.0f), 448.0f); }
__device__ inline uchar f2f8(float v) {
    int r = __builtin_amdgcn_cvt_pk_fp8_f32(clamp8(v), 0.0f, 0, false);
    return (uchar)(r & 0xff);
}
__device__ inline void f8x8_acc(uint2 w, float* acc) {
    f32x2 p;
    p = __builtin_amdgcn_cvt_pk_f32_fp8(w.x, false); acc[0] += p.x; acc[1] += p.y;
    p = __builtin_amdgcn_cvt_pk_f32_fp8(w.x, true);  acc[2] += p.x; acc[3] += p.y;
    p = __builtin_amdgcn_cvt_pk_f32_fp8(w.y, false); acc[4] += p.x; acc[5] += p.y;
    p = __builtin_amdgcn_cvt_pk_f32_fp8(w.y, true);  acc[6] += p.x; acc[7] += p.y;
}
__device__ inline uint2 f8x8_pack(const float* v) {
    uint2 r;
    r.x = (uint)__builtin_amdgcn_cvt_pk_fp8_f32(clamp8(v[0]), clamp8(v[1]), 0, false);
    r.x = (uint)__builtin_amdgcn_cvt_pk_fp8_f32(clamp8(v[2]), clamp8(v[3]), (int)r.x, true);
    r.y = (uint)__builtin_amdgcn_cvt_pk_fp8_f32(clamp8(v[4]), clamp8(v[5]), 0, false);
    r.y = (uint)__builtin_amdgcn_cvt_pk_fp8_f32(clamp8(v[6]), clamp8(v[7]), (int)r.y, true);
    return r;
}

// ---------------- zero gcount (must precede p1cvt) ----------------
__global__ __launch_bounds__(256) void zero_k(int* __restrict__ gcount) {
    gcount[threadIdx.x] = 0;
}

// ---------------- merged launch: CSR P1 (blocks 0..511) + weight cvt (512..543) ----------
__global__ __launch_bounds__(256) void p1cvt_k(const int* __restrict__ eq, const int* __restrict__ ec,
                                               uint* __restrict__ staged, int* __restrict__ gcount,
                                               const float* __restrict__ W1, const float* __restrict__ W2,
                                               const float* __restrict__ W3, ushort* __restrict__ Wt1,
                                               ushort* __restrict__ Wt2, uchar* __restrict__ Wt3f8) {
    int t = threadIdx.x;
    if (blockIdx.x < 512) {
        __shared__ uint s_pk[EPB];
        __shared__ int s_cnt[NBUCK];
        __shared__ int s_off[NBUCK];
        __shared__ int s_base[NBUCK];
        __shared__ int s_gb[NBUCK];
        bool sideB = blockIdx.x >= 256;
        const int* edge = sideB ? ec : eq;
        int off = sideB ? NT : 0;
        int e0 = (blockIdx.x & 255) * EPB;
        s_cnt[t] = 0;
        __syncthreads();
        uint pk[16]; int bk[16];
#pragma unroll
        for (int j = 0; j < 16; j++) {
            int e = e0 + j * 256 + t;
            int s = edge[e] + off;
            int d = edge[NE + e] + off;
            bk[j] = d >> BSHIFT;
            pk[j] = ((uint)s << BSHIFT) | (uint)(d & (BNODES - 1));
            atomicAdd(&s_cnt[bk[j]], 1);
        }
        __syncthreads();
        s_off[t] = s_cnt[t];
        __syncthreads();
        for (int o = 1; o < NBUCK; o <<= 1) {
            int x = (t >= o) ? s_off[t - o] : 0;
            __syncthreads();
            s_off[t] += x;
            __syncthreads();
        }
        {
            int ex = s_off[t] - s_cnt[t];
            s_base[t] = ex;
            s_off[t] = ex;
            s_gb[t] = atomicAdd(&gcount[t], s_cnt[t]);
        }
        __syncthreads();
#pragma unroll
        for (int j = 0; j < 16; j++) {
            int pos = atomicAdd(&s_off[bk[j]], 1);
            s_pk[pos] = pk[j];
        }
        __syncthreads();
        int w = t >> 6, l = t & 63;
        int bsel = l >> 4, l16 = l & 15;
        for (int pb = w; pb < NBUCK / 4; pb += 4) {
            int bkt = pb * 4 + bsel;
            int n = s_cnt[bkt], st = s_base[bkt], gb = s_gb[bkt];
            if (gb + n > BCAP) n = max(0, BCAP - gb);
            for (int i = l16; i < n; i += 16)
                staged[bkt * BCAP + gb + i] = s_pk[st + i];
        }
    } else {
        int i = (blockIdx.x - 512) * 256 + t;   // 0..8191
        if (i < DD * F1C)  { int k = i / F1C, n = i % F1C; Wt1[n * DD + k]  = f2b(W1[i]); }
        if (i < F1C * F2C) { int k = i / F2C, n = i % F2C; Wt2[n * F1C + k] = f2b(W2[i]); }
        if (i < F2C * F3C) { int k = i / F3C, n = i % F3C; Wt3f8[n * F2C + k] = f2f8(W3[i]); }
    }
}

// ---------------- CSR P2 (fused count+scan+place) + feature pre-scale epilogue ----------
__global__ __launch_bounds__(256) void csr_p2_k(const uint* __restrict__ staged, const int* __restrict__ gcount,
                                                int* __restrict__ rp, int* __restrict__ indeg,
                                                float* __restrict__ dinv, int* __restrict__ ep,
                                                const float* __restrict__ xq, const float* __restrict__ xc,
                                                ushort* __restrict__ xb) {
    int b = blockIdx.x;
    int t = threadIdx.x;
    __shared__ int cnt[BNODES];
    __shared__ int fl[BNODES];
    __shared__ int wsum[256];
    __shared__ int gsc[NBUCK];
    __shared__ float sdv[BNODES];
    cnt[t] = 0; cnt[t + 256] = 0;
    gsc[t] = min(gcount[t], BCAP);
    __syncthreads();
    for (int off = 1; off < NBUCK; off <<= 1) {
        int x = (t >= off) ? gsc[t - off] : 0;
        __syncthreads();
        gsc[t] += x;
        __syncthreads();
    }
    int gbase = (b == 0) ? 0 : gsc[b - 1];
    int n = min(gcount[b], BCAP);
    const uint* sb = staged + (size_t)b * BCAP;
    int i = t;
    for (; i + 768 < n; i += 1024) {
        uint p0 = sb[i];
        uint p1 = sb[i + 256];
        uint p2 = sb[i + 512];
        uint p3 = sb[i + 768];
        atomicAdd(&cnt[p0 & (BNODES - 1)], 1);
        atomicAdd(&cnt[p1 & (BNODES - 1)], 1);
        atomicAdd(&cnt[p2 & (BNODES - 1)], 1);
        atomicAdd(&cnt[p3 & (BNODES - 1)], 1);
    }
    for (; i < n; i += 256)
        atomicAdd(&cnt[sb[i] & (BNODES - 1)], 1);
    __syncthreads();
    int base2 = t * 2;
    int c0 = cnt[base2], c1 = cnt[base2 + 1];
    int s2 = c0 + c1;
    wsum[t] = s2;
    __syncthreads();
    for (int off = 1; off < 256; off <<= 1) {
        int x = (t >= off) ? wsum[t - off] : 0;
        __syncthreads();
        wsum[t] += x;
        __syncthreads();
    }
    int p = gbase + wsum[t] - s2;
    int v0 = b * BNODES + base2;
    float d0 = rsqrtf((float)(c0 + 1));
    float d1 = rsqrtf((float)(c1 + 1));
    rp[v0] = p;          fl[base2] = p;
    indeg[v0] = c0;      dinv[v0] = d0;      sdv[base2] = d0;
    p += c0;
    rp[v0 + 1] = p;      fl[base2 + 1] = p;
    indeg[v0 + 1] = c1;  dinv[v0 + 1] = d1;  sdv[base2 + 1] = d1;
    __syncthreads();
    i = t;
    for (; i + 768 < n; i += 1024) {
        uint p0 = sb[i];
        uint p1 = sb[i + 256];
        uint p2 = sb[i + 512];
        uint p3 = sb[i + 768];
        ep[atomicAdd(&fl[p0 & (BNODES - 1)], 1)] = (int)(p0 >> BSHIFT);
        ep[atomicAdd(&fl[p1 & (BNODES - 1)], 1)] = (int)(p1 >> BSHIFT);
        ep[atomicAdd(&fl[p2 & (BNODES - 1)], 1)] = (int)(p2 >> BSHIFT);
        ep[atomicAdd(&fl[p3 & (BNODES - 1)], 1)] = (int)(p3 >> BSHIFT);
    }
    for (; i < n; i += 256) {
        uint pk = sb[i];
        ep[atomicAdd(&fl[pk & (BNODES - 1)], 1)] = (int)(pk >> BSHIFT);
    }
    // ---- epilogue: pre-scaled bf16 features for this block's 512 vertices ----
    {
        const float* xs = (b < 128) ? (xq + (size_t)b * BNODES * DD)
                                    : (xc + ((size_t)b * BNODES - NT) * DD);
        ushort* xd = xb + (size_t)b * BNODES * DD;
        for (int g = t; g < BNODES * DD / 4; g += 256) {
            int r = g >> 3;                 // 8 float4 per 32-f row
            float4 v = ((const float4*)xs)[g];
            float dv = sdv[r];
            ushort4 o;
            o.x = f2b(v.x * dv); o.y = f2b(v.y * dv);
            o.z = f2b(v.z * dv); o.w = f2b(v.w * dv);
            ((ushort4*)xd)[g] = o;
        }
    }
}

// ---------------- GCN aggregation, bf16 rows (layer 1, F=32) — R0 structure, plain loads --
__global__ __launch_bounds__(256) void agg_bf_k(const ushort* __restrict__ in, const int* __restrict__ rp,
                                                const int* __restrict__ indeg, const int* __restrict__ ep,
                                                const float* __restrict__ dinv,
                                                ushort* __restrict__ out) {
    int g = threadIdx.x >> 2;          // 64 vertices per block
    int l = threadIdx.x & 3;           // 4 lanes x 8 bf16 = 64 B row
    int v = blockIdx.x * 64 + g;
    float dv = dinv[v];
    short8 rs = *(const short8*)(in + (size_t)v * 32 + l * 8);
    float acc[8];
#pragma unroll
    for (int j = 0; j < 8; j++) acc[j] = b2f((ushort)rs[j]);   // self loop (pre-scaled)
    int start = rp[v];
    int cnt   = indeg[v];
    int i = 0;
    for (; i + 4 <= cnt; i += 4) {
        int s0 = ep[start + i];
        int s1 = ep[start + i + 1];
        int s2 = ep[start + i + 2];
        int s3 = ep[start + i + 3];
        short8 r0 = *(const short8*)(in + (size_t)s0 * 32 + l * 8);
        short8 r1 = *(const short8*)(in + (size_t)s1 * 32 + l * 8);
        short8 r2 = *(const short8*)(in + (size_t)s2 * 32 + l * 8);
        short8 r3 = *(const short8*)(in + (size_t)s3 * 32 + l * 8);
#pragma unroll
        for (int j = 0; j < 8; j++) {
            acc[j] += b2f((ushort)r0[j]);
            acc[j] += b2f((ushort)r1[j]);
            acc[j] += b2f((ushort)r2[j]);
            acc[j] += b2f((ushort)r3[j]);
        }
    }
    for (; i < cnt; i++) {
        int s0 = ep[start + i];
        short8 r0 = *(const short8*)(in + (size_t)s0 * 32 + l * 8);
#pragma unroll
        for (int j = 0; j < 8; j++) acc[j] += b2f((ushort)r0[j]);
    }
    short8 o;
#pragma unroll
    for (int j = 0; j < 8; j++) o[j] = (short)f2b(dv * acc[j]);
    *(short8*)(out + (size_t)v * 32 + l * 8) = o;
}

// ---------------- GCN aggregation, fp8 rows (F=64) — R0 structure, plain loads -----------
template<bool OUT_BF16, bool BIAS, bool RELU>
__global__ __launch_bounds__(256) void agg_f8_k(const uchar* __restrict__ in, const int* __restrict__ rp,
                                                const int* __restrict__ indeg, const int* __restrict__ ep,
                                                const float* __restrict__ dinv,
                                                const float* __restrict__ bias, void* __restrict__ outp) {
    int g = threadIdx.x >> 3;          // 32 vertices per block
    int l = threadIdx.x & 7;           // 8 lanes x 8 fp8 = 64 B row
    int v = blockIdx.x * 32 + g;
    float dv = dinv[v];
    float acc[8] = {0, 0, 0, 0, 0, 0, 0, 0};
    f8x8_acc(*(const uint2*)(in + (size_t)v * 64 + l * 8), acc);   // self term
    int start = rp[v];
    int cnt   = indeg[v];
    int i = 0;
    for (; i + 8 <= cnt; i += 8) {     // 8 gathers in flight per lane
        int sx[8];
#pragma unroll
        for (int j = 0; j < 8; j++) sx[j] = ep[start + i + j];
        uint2 gx[8];
#pragma unroll
        for (int j = 0; j < 8; j++) gx[j] = *(const uint2*)(in + (size_t)sx[j] * 64 + l * 8);
#pragma unroll
        for (int j = 0; j < 8; j++) f8x8_acc(gx[j], acc);
    }
    for (; i + 4 <= cnt; i += 4) {
        int s0 = ep[start + i];
        int s1 = ep[start + i + 1];
        int s2 = ep[start + i + 2];
        int s3 = ep[start + i + 3];
        uint2 g0 = *(const uint2*)(in + (size_t)s0 * 64 + l * 8);
        uint2 g1 = *(const uint2*)(in + (size_t)s1 * 64 + l * 8);
        uint2 g2 = *(const uint2*)(in + (size_t)s2 * 64 + l * 8);
        uint2 g3 = *(const uint2*)(in + (size_t)s3 * 64 + l * 8);
        f8x8_acc(g0, acc); f8x8_acc(g1, acc); f8x8_acc(g2, acc); f8x8_acc(g3, acc);
    }
    for (; i < cnt; i++) {
        int s0 = ep[start + i];
        f8x8_acc(*(const uint2*)(in + (size_t)s0 * 64 + l * 8), acc);
    }
#pragma unroll
    for (int j = 0; j < 8; j++) {
        float x = dv * acc[j];
        if (BIAS) x += bias[l * 8 + j];
        if (RELU) x = fmaxf(x, 0.0f);
        acc[j] = x;
    }
    if (OUT_BF16) {
        short8 o;
#pragma unroll
        for (int j = 0; j < 8; j++) o[j] = (short)f2b(acc[j]);
        *(short8*)((ushort*)outp + (size_t)v * 64 + l * 8) = o;
    } else {
        *(uint2*)((uchar*)outp + (size_t)v * 64 + l * 8) = f8x8_pack(acc);
    }
}

// ---------------- fused GEMM1+GEMM2: h1=relu(xa@W1+b1) [LDS] ; h8a=(h1@W2)*dinv ----------
__global__ __launch_bounds__(256) void gemm12_k(const ushort* __restrict__ xa,
                                                const ushort* __restrict__ Wt1,
                                                const float* __restrict__ b1,
                                                const ushort* __restrict__ Wt2,
                                                const float* __restrict__ dinv,
                                                uchar* __restrict__ h8a) {
    __shared__ ushort s_h1[128][136];
    int w = threadIdx.x >> 6, lane = threadIdx.x & 63;
    int r16 = lane & 15, quad = lane >> 4, koff = quad * 8;
    size_t rows0 = (size_t)blockIdx.x * 128;

    short8 af1[2];
#pragma unroll
    for (int mt = 0; mt < 2; mt++)
        af1[mt] = *(const short8*)(xa + (rows0 + (w * 2 + mt) * 16 + r16) * 32 + koff);
#pragma unroll
    for (int nt = 0; nt < 8; nt++) {
        short8 bfr = *(const short8*)(Wt1 + (size_t)(nt * 16 + r16) * 32 + koff);
        f32x4 acc[2] = {{0.f,0.f,0.f,0.f},{0.f,0.f,0.f,0.f}};
        acc[0] = __builtin_amdgcn_mfma_f32_16x16x32_bf16(af1[0], bfr, acc[0], 0, 0, 0);
        acc[1] = __builtin_amdgcn_mfma_f32_16x16x32_bf16(af1[1], bfr, acc[1], 0, 0, 0);
        int col = nt * 16 + r16;
        float bc = b1[col];
#pragma unroll
        for (int mt = 0; mt < 2; mt++)
#pragma unroll
            for (int r = 0; r < 4; r++) {
                int rl = (w * 2 + mt) * 16 + quad * 4 + r;
                s_h1[rl][col] = f2b(fmaxf(acc[mt][r] + bc, 0.0f));
            }
    }
    __syncthreads();

    short8 af2[4][2];
#pragma unroll
    for (int kc = 0; kc < 4; kc++)
#pragma unroll
        for (int mt = 0; mt < 2; mt++)
            af2[kc][mt] = *(const short8*)&s_h1[(w * 2 + mt) * 16 + r16][kc * 32 + koff];
    float dvr[2][4];
#pragma unroll
    for (int mt = 0; mt < 2; mt++)
#pragma unroll
        for (int r = 0; r < 4; r++)
            dvr[mt][r] = dinv[rows0 + (w * 2 + mt) * 16 + quad * 4 + r];
#pragma unroll
    for (int nt = 0; nt < 4; nt++) {
        f32x4 acc[2] = {{0.f,0.f,0.f,0.f},{0.f,0.f,0.f,0.f}};
#pragma unroll
        for (int kc = 0; kc < 4; kc++) {
            short8 bfr = *(const short8*)(Wt2 + (size_t)(nt * 16 + r16) * 128 + kc * 32 + koff);
            acc[0] = __builtin_amdgcn_mfma_f32_16x16x32_bf16(af2[kc][0], bfr, acc[0], 0, 0, 0);
            acc[1] = __builtin_amdgcn_mfma_f32_16x16x32_bf16(af2[kc][1], bfr, acc[1], 0, 0, 0);
        }
#pragma unroll
        for (int mt = 0; mt < 2; mt++)
#pragma unroll
            for (int r = 0; r < 4; r++) {
                size_t row = rows0 + (w * 2 + mt) * 16 + quad * 4 + r;
                int col = nt * 16 + r16;
                h8a[row * 64 + col] = f2f8(acc[mt][r] * dvr[mt][r]);
            }
    }
}

// ---------------- fp8 GEMM via MFMA (K=64, N=64) ----------------
__global__ __launch_bounds__(256) void gemm_f8_k(const uchar* __restrict__ A8,
                                                 const uchar* __restrict__ Wt8,
                                                 const float* __restrict__ dinv,
                                                 uchar* __restrict__ out8) {
    int w = threadIdx.x >> 6, lane = threadIdx.x & 63;
    int r16 = lane & 15, koff = (lane >> 4) * 8;
    size_t rows0 = (size_t)blockIdx.x * 128;

    long af[2][2];
#pragma unroll
    for (int kc = 0; kc < 2; kc++)
#pragma unroll
        for (int mt = 0; mt < 2; mt++)
            af[kc][mt] = *(const long*)(A8 + (rows0 + (w * 2 + mt) * 16 + r16) * 64 + kc * 32 + koff);

    float dvr[2][4];
#pragma unroll
    for (int mt = 0; mt < 2; mt++)
#pragma unroll
        for (int r = 0; r < 4; r++)
            dvr[mt][r] = dinv[rows0 + (w * 2 + mt) * 16 + (lane >> 4) * 4 + r];

#pragma unroll
    for (int nt = 0; nt < 4; nt++) {
        f32x4 acc[2] = {{0.f,0.f,0.f,0.f},{0.f,0.f,0.f,0.f}};
#pragma unroll
        for (int kc = 0; kc < 2; kc++) {
            long b = *(const long*)(Wt8 + (size_t)(nt * 16 + r16) * 64 + kc * 32 + koff);
            acc[0] = __builtin_amdgcn_mfma_f32_16x16x32_fp8_fp8(af[kc][0], b, acc[0], 0, 0, 0);
            acc[1] = __builtin_amdgcn_mfma_f32_16x16x32_fp8_fp8(af[kc][1], b, acc[1], 0, 0, 0);
        }
#pragma unroll
        for (int mt = 0; mt < 2; mt++) {
#pragma unroll
            for (int r = 0; r < 4; r++) {
                size_t row = rows0 + (w * 2 + mt) * 16 + (lane >> 4) * 4 + r;
                int col = nt * 16 + (lane & 15);
                out8[row * 64 + col] = f2f8(acc[mt][r] * dvr[mt][r]);
            }
        }
    }
}

// ---------------- fused tail v3: S kept in registers (single MFMA pass) ----------------
// 256 blocks x 1024 threads (1 block/CU). Waves 0-7 pool q, waves 8-15 pool c.
// Hist pass A stores its 64 S-values/thread in VGPRs (16 x f32x4, static indexing);
// pass B bins from registers -- no MFMA recompute, no c_s re-reads. VGPR ~128 = still
// 4 waves/SIMD at 1024 threads. Arithmetic identical (same f32 values -> same bins).
__global__ __launch_bounds__(1024) void tail_k(const ushort* __restrict__ fin,
                                               const int* __restrict__ qsz, const int* __restrict__ csz,
                                               const float* __restrict__ attn_w,
                                               const float* __restrict__ A, const float* __restrict__ bw,
                                               const float* __restrict__ ntn_bias,
                                               const float* __restrict__ fc1w, const float* __restrict__ fc1b,
                                               const float* __restrict__ fc2w, const float* __restrict__ fc2b,
                                               float* __restrict__ out) {
    __shared__ ushort q_s[256][72];     // 36.9 KB
    __shared__ ushort c_s[256][72];     // 36.9 KB
    __shared__ ushort h[16 * 1024];     // 32 KB
    __shared__ int hp[16 * 64];         // 4 KB
    __shared__ float s_red[2][512];     // 4 KB  (per-side pool partials)
    __shared__ float s_sq2[2][64], s_ctx2[2][64], s_sig2[2][256];
    __shared__ float smn[16], smx[16], s_sc[2];
    __shared__ float s_e[2][64];
    __shared__ float s_ntn[16], s_s[32], s_a[16];
    __shared__ int s_hist[16];

    int b = blockIdx.x;
    int t = threadIdx.x;
    int f = t & 63;                    // lane
    int w = t >> 6;                    // wave 0..15
    int r16 = f & 15, koff = (f >> 4) * 8;
    int side = w >> 3;                 // 0 = q, 1 = c
    int w8 = w & 7;                    // wave within side
    ushort (*tile)[72] = side ? c_s : q_s;
    const ushort* qb = fin + (size_t)b * NN * 64;
    const ushort* cb = fin + (size_t)(NT + b * NN) * 64;

    // ---- phase 1: stage both tiles once ----
#pragma unroll
    for (int it = 0; it < 2; it++) {
        int idx = it * 8192 + t * 8;
        int row = idx >> 6, f0 = idx & 63;
        *(short8*)&q_s[row][f0] = *(const short8*)(qb + idx);
        *(short8*)&c_s[row][f0] = *(const short8*)(cb + idx);
    }
    __syncthreads();                               // B1

    // ---- phase 2: hist pass A (S -> registers, min/max) + pool column-sums ----
    f32x4 sacc[16];
    {
        short8 a0, a1;
        int qrow = w * 16 + r16;
        a0 = *(const short8*)&q_s[qrow][koff];
        a1 = *(const short8*)&q_s[qrow][32 + koff];
        float mn = 1e30f, mx = -1e30f;
#pragma unroll
        for (int mt = 0; mt < 16; mt++) {
            int crow = mt * 16 + r16;
            short8 b0 = *(const short8*)&c_s[crow][koff];
            short8 b1 = *(const short8*)&c_s[crow][32 + koff];
            f32x4 acc = {0.0f, 0.0f, 0.0f, 0.0f};
            acc = __builtin_amdgcn_mfma_f32_16x16x32_bf16(a0, b0, acc, 0, 0, 0);
            acc = __builtin_amdgcn_mfma_f32_16x16x32_bf16(a1, b1, acc, 0, 0, 0);
            sacc[mt] = acc;
            mn = fminf(mn, fminf(fminf(acc[0], acc[1]), fminf(acc[2], acc[3])));
            mx = fmaxf(mx, fmaxf(fmaxf(acc[0], acc[1]), fmaxf(acc[2], acc[3])));
        }
        for (int off = 32; off; off >>= 1) {
            mn = fminf(mn, __shfl_xor(mn, off, 64));
            mx = fmaxf(mx, __shfl_xor(mx, off, 64));
        }
        if (f == 0) { smn[w] = mn; smx[w] = mx; }
    }
    {
        float psum = 0.0f;
#pragma unroll 8
        for (int i2 = 0; i2 < 32; i2++) psum += b2f(tile[w8 * 32 + i2][f]);
        s_red[side][w8 * 64 + f] = psum;
    }
    __syncthreads();                               // B2

    // ---- phase 3: scale (t==0) + ctx (one wave per side) + h init (all) ----
    if (t == 0) {
        float m0 = smn[0], m1 = smx[0];
#pragma unroll
        for (int j = 1; j < 16; j++) {
            m0 = fminf(m0, smn[j]);
            m1 = fmaxf(m1, smx[j]);
        }
        s_sc[0] = m0;
        s_sc[1] = 16.0f / fmaxf(m1 - m0, 1e-12f);
    }
    if (w8 == 0) {
        float s = 0.0f;
#pragma unroll
        for (int j = 0; j < 8; j++) s += s_red[side][j * 64 + f];
        s_sq2[side][f] = s;
        float acc = 0.0f;
        for (int k = 0; k < 64; k++) acc += s_sq2[side][k] * attn_w[k * 64 + f];
        float sz = (float)((side ? csz : qsz)[b]);
        s_ctx2[side][f] = tanhf(acc / sz);
    }
#pragma unroll
    for (int i = 0; i < 16; i++) h[i * 1024 + t] = 0;
    __syncthreads();                               // B3

    // ---- phase 4: hist pass B (bin from REGISTERS) + sig (4 waves per side) ----
    {
        float bmn = s_sc[0], bscale = s_sc[1];
#pragma unroll
        for (int mt = 0; mt < 16; mt++) {
            f32x4 acc = sacc[mt];
#pragma unroll
            for (int r = 0; r < 4; r++) {
                int bin = (int)floorf((acc[r] - bmn) * bscale);
                bin = min(max(bin, 0), 15);
                h[bin * 1024 + t] += 1;
            }
        }
    }
    {
        int lt = t & 511;
        if (lt < 256) {
            float acc = 0.0f;
#pragma unroll 8
            for (int k = 0; k < 64; k++) acc += b2f(tile[lt][k]) * s_ctx2[side][k];
            s_sig2[side][lt] = 1.0f / (1.0f + expf(-acc));
        }
    }
    __syncthreads();                               // B4

    // ---- phase 5: hist partial reduce + pool weighted col-sums ----
    {
        int bb = t >> 6, part = t & 63;
        int sum = 0;
#pragma unroll
        for (int j = 0; j < 16; j++) sum += (int)h[bb * 1024 + part * 16 + j];
        hp[bb * 64 + part] = sum;
    }
    {
        float eacc = 0.0f;
#pragma unroll 8
        for (int i = 0; i < 32; i++) {
            int n = w8 * 32 + i;
            eacc += s_sig2[side][n] * b2f(tile[n][f]);
        }
        s_red[side][w8 * 64 + f] = eacc;
    }
    __syncthreads();                               // B5

    // ---- phase 6: hist final (t<16) + e final (one wave per side) ----
    if (t < 16) {
        int s = 0;
#pragma unroll
        for (int j = 0; j < 64; j++) s += hp[t * 64 + j];
        s_hist[t] = s;
    }
    if (w8 == 0) {
        float s = 0.0f;
#pragma unroll
        for (int j = 0; j < 8; j++) s += s_red[side][j * 64 + f];
        s_e[side][f] = s;
    }
    __syncthreads();                               // B6

    // ---- phase 7: NTN einsum (all waves; wave w = slice tt, lane f = i) ----
    {
        const float4* Ar = (const float4*)(A + (size_t)t * 64);
        float acc = 0.0f;
#pragma unroll
        for (int j = 0; j < 16; j++) {
            float4 a4 = Ar[j];
            acc += a4.x * s_e[1][4 * j] + a4.y * s_e[1][4 * j + 1]
                 + a4.z * s_e[1][4 * j + 2] + a4.w * s_e[1][4 * j + 3];
        }
        float p = s_e[0][f] * acc;
        for (int off = 32; off; off >>= 1) p += __shfl_xor(p, off, 64);
        if (f == 0) s_ntn[w] = p;
    }
    __syncthreads();                               // B7
    if (t < 16) {
        float acc = s_ntn[t] + ntn_bias[t];
        for (int k = 0; k < 64; k++) acc += s_e[0][k] * bw[k * 16 + t];
        for (int k = 0; k < 64; k++) acc += s_e[1][k] * bw[(64 + k) * 16 + t];
        s_s[t] = fmaxf(acc, 0.0f);
        s_s[16 + t] = (float)s_hist[t] * (1.0f / 65536.0f);
    }
    __syncthreads();                               // B8
    if (t < 16) {
        float aa = fc1b[t];
        for (int k = 0; k < 32; k++) aa += s_s[k] * fc1w[k * 16 + t];
        s_a[t] = fmaxf(aa, 0.0f);
    }
    __syncthreads();                               // B9
    if (t == 0) {
        float z = fc2b[0];
        for (int j = 0; j < 16; j++) z += s_a[j] * fc2w[j];
        float nz = -z;
        float sp = (nz > 20.0f) ? nz : log1pf(expf(nz));   // stable -log(sigmoid(z))
        out[b] = 0.5f * (float)(qsz[b] + csz[b]) * sp;
    }
}

// ---------------- launch ----------------
extern "C" void kernel_launch(void* const* d_in, const int* in_sizes, int n_in,
                              void* d_out, int out_size, void* d_ws, size_t ws_size,
                              hipStream_t stream) {
    const float* x_q    = (const float*)d_in[0];
    const int*   edge_q = (const int*)d_in[1];
    const float* x_c    = (const float*)d_in[2];
    const int*   edge_c = (const int*)d_in[3];
    const int*   qsz    = (const int*)d_in[4];
    const int*   csz    = (const int*)d_in[5];
    const float* W1 = (const float*)d_in[6];
    const float* b1 = (const float*)d_in[7];
    const float* W2 = (const float*)d_in[8];
    const float* b2 = (const float*)d_in[9];
    const float* W3 = (const float*)d_in[10];
    const float* b3 = (const float*)d_in[11];
    const float* attn_w  = (const float*)d_in[12];
    const float* ntn_a   = (const float*)d_in[13];
    const float* ntn_b   = (const float*)d_in[14];
    const float* ntn_bias= (const float*)d_in[15];
    const float* fc1w = (const float*)d_in[16];
    const float* fc1b = (const float*)d_in[17];
    const float* fc2w = (const float*)d_in[18];
    const float* fc2b = (const float*)d_in[19];
    float* out = (float*)d_out;

    char* w = (char*)d_ws;
    auto alloc = [&](size_t bytes) -> void* {
        void* p = (void*)w;
        w += (bytes + 255) & ~(size_t)255;
        return p;
    };
    int*    rp     = (int*)alloc((size_t)NT2 * 4);
    int*    indeg  = (int*)alloc((size_t)NT2 * 4);
    float*  dinv   = (float*)alloc((size_t)NT2 * 4);
    int*    gcount = (int*)alloc(NBUCK * 4);
    uint*   staged = (uint*)alloc((size_t)NBUCK * BCAP * 4);   // 10.5 MB packed
    int*    ep     = (int*)alloc((size_t)2 * NE * 4);           // 8.4 MB (src only)
    ushort* xb     = (ushort*)alloc((size_t)NT2 * 32 * 2);      // pre-scaled bf16 features
    ushort* xa     = (ushort*)alloc((size_t)NT2 * 32 * 2);      // agg1 output (bf16)
    uchar*  h8a    = (uchar*)alloc((size_t)NT2 * 64);           // fp8 64-d scratch
    uchar*  h8b    = (uchar*)alloc((size_t)NT2 * 64);           // fp8 64-d scratch
    ushort* fin    = (ushort*)alloc((size_t)NT2 * 64 * 2);      // qfin | cfin (bf16)
    ushort* Wt1    = (ushort*)alloc((size_t)DD * F1C * 2);
    ushort* Wt2    = (ushort*)alloc((size_t)F1C * F2C * 2);
    uchar*  Wt3f8  = (uchar*)alloc((size_t)F2C * F3C);

    // CSR build + weight cvt; p2 fuses the dinv feature pre-scale epilogue
    zero_k<<<1, 256, 0, stream>>>(gcount);
    p1cvt_k<<<512 + 32, 256, 0, stream>>>(edge_q, edge_c, staged, gcount,
                                          W1, W2, W3, Wt1, Wt2, Wt3f8);
    csr_p2_k<<<NBUCK, 256, 0, stream>>>(staged, gcount, rp, indeg, dinv, ep,
                                        x_q, x_c, xb);

    // GNN: standalone full-occupancy aggs (best-measured gather regime) + MFMA GEMMs
    agg_bf_k<<<NT2 / 64, 256, 0, stream>>>(xb, rp, indeg, ep, dinv, xa);
    gemm12_k<<<NT2 / 128, 256, 0, stream>>>(xa, Wt1, b1, Wt2, dinv, h8a);
    agg_f8_k<false, true, true><<<NT2 / 32, 256, 0, stream>>>(h8a, rp, indeg, ep, dinv, b2, h8b);
    gemm_f8_k<<<NT2 / 128, 256, 0, stream>>>(h8b, Wt3f8, dinv, h8a);
    agg_f8_k<true, true, false><<<NT2 / 32, 256, 0, stream>>>(h8a, rp, indeg, ep, dinv, b3, fin);

    // fused tail v3 (S in registers), writes out[b] directly
    tail_k<<<BB, 1024, 0, stream>>>(fin, qsz, csz, attn_w, ntn_a, ntn_b, ntn_bias,
                                    fc1w, fc1b, fc2w, fc2b, out);
}

// Round 14
// 274.750 us; speedup vs baseline: 1.0498x; 1.0498x over previous
//
#include <hip/hip_runtime.h>
#include <hip/hip_bf16.h>
#include <math.h>

// Problem constants (from reference)
#define BB 256
#define NN 256
#define NT (BB*NN)        // 65536 nodes per side
#define NT2 (2*NT)        // unified graph: both sides, side-1 ids offset by NT
#define NE (NT*16)        // 1048576 directed edges per side
#define DD 32
#define F1C 128
#define F2C 64
#define F3C 64
#define TT 16
#define BINS 16

// CSR bucket build (unified graph)
#define NBUCK 256
#define BSHIFT 9
#define BNODES 512
#define BCAP 10240
#define EPB 4096

typedef __attribute__((ext_vector_type(8))) short short8;   // 8 bf16 in 4 VGPRs
typedef __attribute__((ext_vector_type(4))) float f32x4;    // MFMA accumulator
typedef __attribute__((ext_vector_type(2))) float f32x2;

__device__ inline float b2f(ushort u) { return __uint_as_float(((uint)u) << 16); }
__device__ inline ushort f2b(float f) {
    uint u = __float_as_uint(f);
    return (ushort)((u + 0x7fffu + ((u >> 16) & 1u)) >> 16);
}
// fp8 e4m3 helpers (clamp to +-448 so saturation can never produce NaN)
__device__ inline float clamp8(float v) { return fminf(fmaxf(v, -448.0f), 448.0f); }
__device__ inline uchar f2f8(float v) {
    int r = __builtin_amdgcn_cvt_pk_fp8_f32(clamp8(v), 0.0f, 0, false);
    return (uchar)(r & 0xff);
}
__device__ inline void f8x8_acc(uint2 w, float* acc) {
    f32x2 p;
    p = __builtin_amdgcn_cvt_pk_f32_fp8(w.x, false); acc[0] += p.x; acc[1] += p.y;
    p = __builtin_amdgcn_cvt_pk_f32_fp8(w.x, true);  acc[2] += p.x; acc[3] += p.y;
    p = __builtin_amdgcn_cvt_pk_f32_fp8(w.y, false); acc[4] += p.x; acc[5] += p.y;
    p = __builtin_amdgcn_cvt_pk_f32_fp8(w.y, true);  acc[6] += p.x; acc[7] += p.y;
}
__device__ inline uint2 f8x8_pack(const float* v) {
    uint2 r;
    r.x = (uint)__builtin_amdgcn_cvt_pk_fp8_f32(clamp8(v[0]), clamp8(v[1]), 0, false);
    r.x = (uint)__builtin_amdgcn_cvt_pk_fp8_f32(clamp8(v[2]), clamp8(v[3]), (int)r.x, true);
    r.y = (uint)__builtin_amdgcn_cvt_pk_fp8_f32(clamp8(v[4]), clamp8(v[5]), 0, false);
    r.y = (uint)__builtin_amdgcn_cvt_pk_fp8_f32(clamp8(v[6]), clamp8(v[7]), (int)r.y, true);
    return r;
}

// ---------------- zero gcount (must precede p1cvt) ----------------
__global__ __launch_bounds__(256) void zero_k(int* __restrict__ gcount) {
    gcount[threadIdx.x] = 0;
}

// ---------------- merged launch: CSR P1 (blocks 0..511) + weight cvt (512..543) ----------
__global__ __launch_bounds__(256) void p1cvt_k(const int* __restrict__ eq, const int* __restrict__ ec,
                                               uint* __restrict__ staged, int* __restrict__ gcount,
                                               const float* __restrict__ W1, const float* __restrict__ W2,
                                               const float* __restrict__ W3, ushort* __restrict__ Wt1,
                                               ushort* __restrict__ Wt2, uchar* __restrict__ Wt3f8) {
    int t = threadIdx.x;
    if (blockIdx.x < 512) {
        __shared__ uint s_pk[EPB];
        __shared__ int s_cnt[NBUCK];
        __shared__ int s_off[NBUCK];
        __shared__ int s_base[NBUCK];
        __shared__ int s_gb[NBUCK];
        bool sideB = blockIdx.x >= 256;
        const int* edge = sideB ? ec : eq;
        int off = sideB ? NT : 0;
        int e0 = (blockIdx.x & 255) * EPB;
        s_cnt[t] = 0;
        __syncthreads();
        uint pk[16]; int bk[16];
#pragma unroll
        for (int j = 0; j < 16; j++) {
            int e = e0 + j * 256 + t;
            int s = edge[e] + off;
            int d = edge[NE + e] + off;
            bk[j] = d >> BSHIFT;
            pk[j] = ((uint)s << BSHIFT) | (uint)(d & (BNODES - 1));
            atomicAdd(&s_cnt[bk[j]], 1);
        }
        __syncthreads();
        s_off[t] = s_cnt[t];
        __syncthreads();
        for (int o = 1; o < NBUCK; o <<= 1) {
            int x = (t >= o) ? s_off[t - o] : 0;
            __syncthreads();
            s_off[t] += x;
            __syncthreads();
        }
        {
            int ex = s_off[t] - s_cnt[t];
            s_base[t] = ex;
            s_off[t] = ex;
            s_gb[t] = atomicAdd(&gcount[t], s_cnt[t]);
        }
        __syncthreads();
#pragma unroll
        for (int j = 0; j < 16; j++) {
            int pos = atomicAdd(&s_off[bk[j]], 1);
            s_pk[pos] = pk[j];
        }
        __syncthreads();
        int w = t >> 6, l = t & 63;
        int bsel = l >> 4, l16 = l & 15;
        for (int pb = w; pb < NBUCK / 4; pb += 4) {
            int bkt = pb * 4 + bsel;
            int n = s_cnt[bkt], st = s_base[bkt], gb = s_gb[bkt];
            if (gb + n > BCAP) n = max(0, BCAP - gb);
            for (int i = l16; i < n; i += 16)
                staged[bkt * BCAP + gb + i] = s_pk[st + i];
        }
    } else {
        int i = (blockIdx.x - 512) * 256 + t;   // 0..8191
        if (i < DD * F1C)  { int k = i / F1C, n = i % F1C; Wt1[n * DD + k]  = f2b(W1[i]); }
        if (i < F1C * F2C) { int k = i / F2C, n = i % F2C; Wt2[n * F1C + k] = f2b(W2[i]); }
        if (i < F2C * F3C) { int k = i / F3C, n = i % F3C; Wt3f8[n * F2C + k] = f2f8(W3[i]); }
    }
}

// ---------------- CSR P2 (fused count+scan+place) + feature pre-scale epilogue ----------
__global__ __launch_bounds__(256) void csr_p2_k(const uint* __restrict__ staged, const int* __restrict__ gcount,
                                                int* __restrict__ rp, int* __restrict__ indeg,
                                                float* __restrict__ dinv, int* __restrict__ ep,
                                                const float* __restrict__ xq, const float* __restrict__ xc,
                                                ushort* __restrict__ xb) {
    int b = blockIdx.x;
    int t = threadIdx.x;
    __shared__ int cnt[BNODES];
    __shared__ int fl[BNODES];
    __shared__ int wsum[256];
    __shared__ int gsc[NBUCK];
    __shared__ float sdv[BNODES];
    cnt[t] = 0; cnt[t + 256] = 0;
    gsc[t] = min(gcount[t], BCAP);
    __syncthreads();
    for (int off = 1; off < NBUCK; off <<= 1) {
        int x = (t >= off) ? gsc[t - off] : 0;
        __syncthreads();
        gsc[t] += x;
        __syncthreads();
    }
    int gbase = (b == 0) ? 0 : gsc[b - 1];
    int n = min(gcount[b], BCAP);
    const uint* sb = staged + (size_t)b * BCAP;
    int i = t;
    for (; i + 768 < n; i += 1024) {
        uint p0 = sb[i];
        uint p1 = sb[i + 256];
        uint p2 = sb[i + 512];
        uint p3 = sb[i + 768];
        atomicAdd(&cnt[p0 & (BNODES - 1)], 1);
        atomicAdd(&cnt[p1 & (BNODES - 1)], 1);
        atomicAdd(&cnt[p2 & (BNODES - 1)], 1);
        atomicAdd(&cnt[p3 & (BNODES - 1)], 1);
    }
    for (; i < n; i += 256)
        atomicAdd(&cnt[sb[i] & (BNODES - 1)], 1);
    __syncthreads();
    int base2 = t * 2;
    int c0 = cnt[base2], c1 = cnt[base2 + 1];
    int s2 = c0 + c1;
    wsum[t] = s2;
    __syncthreads();
    for (int off = 1; off < 256; off <<= 1) {
        int x = (t >= off) ? wsum[t - off] : 0;
        __syncthreads();
        wsum[t] += x;
        __syncthreads();
    }
    int p = gbase + wsum[t] - s2;
    int v0 = b * BNODES + base2;
    float d0 = rsqrtf((float)(c0 + 1));
    float d1 = rsqrtf((float)(c1 + 1));
    rp[v0] = p;          fl[base2] = p;
    indeg[v0] = c0;      dinv[v0] = d0;      sdv[base2] = d0;
    p += c0;
    rp[v0 + 1] = p;      fl[base2 + 1] = p;
    indeg[v0 + 1] = c1;  dinv[v0 + 1] = d1;  sdv[base2 + 1] = d1;
    __syncthreads();
    i = t;
    for (; i + 768 < n; i += 1024) {
        uint p0 = sb[i];
        uint p1 = sb[i + 256];
        uint p2 = sb[i + 512];
        uint p3 = sb[i + 768];
        ep[atomicAdd(&fl[p0 & (BNODES - 1)], 1)] = (int)(p0 >> BSHIFT);
        ep[atomicAdd(&fl[p1 & (BNODES - 1)], 1)] = (int)(p1 >> BSHIFT);
        ep[atomicAdd(&fl[p2 & (BNODES - 1)], 1)] = (int)(p2 >> BSHIFT);
        ep[atomicAdd(&fl[p3 & (BNODES - 1)], 1)] = (int)(p3 >> BSHIFT);
    }
    for (; i < n; i += 256) {
        uint pk = sb[i];
        ep[atomicAdd(&fl[pk & (BNODES - 1)], 1)] = (int)(pk >> BSHIFT);
    }
    // ---- epilogue: pre-scaled bf16 features for this block's 512 vertices ----
    {
        const float* xs = (b < 128) ? (xq + (size_t)b * BNODES * DD)
                                    : (xc + ((size_t)b * BNODES - NT) * DD);
        ushort* xd = xb + (size_t)b * BNODES * DD;
        for (int g = t; g < BNODES * DD / 4; g += 256) {
            int r = g >> 3;                 // 8 float4 per 32-f row
            float4 v = ((const float4*)xs)[g];
            float dv = sdv[r];
            ushort4 o;
            o.x = f2b(v.x * dv); o.y = f2b(v.y * dv);
            o.z = f2b(v.z * dv); o.w = f2b(v.w * dv);
            ((ushort4*)xd)[g] = o;
        }
    }
}

// ---------------- GCN aggregation, bf16 rows (layer 1, F=32) — R0 structure, plain loads --
__global__ __launch_bounds__(256) void agg_bf_k(const ushort* __restrict__ in, const int* __restrict__ rp,
                                                const int* __restrict__ indeg, const int* __restrict__ ep,
                                                const float* __restrict__ dinv,
                                                ushort* __restrict__ out) {
    int g = threadIdx.x >> 2;          // 64 vertices per block
    int l = threadIdx.x & 3;           // 4 lanes x 8 bf16 = 64 B row
    int v = blockIdx.x * 64 + g;
    float dv = dinv[v];
    short8 rs = *(const short8*)(in + (size_t)v * 32 + l * 8);
    float acc[8];
#pragma unroll
    for (int j = 0; j < 8; j++) acc[j] = b2f((ushort)rs[j]);   // self loop (pre-scaled)
    int start = rp[v];
    int cnt   = indeg[v];
    int i = 0;
    for (; i + 4 <= cnt; i += 4) {
        int s0 = ep[start + i];
        int s1 = ep[start + i + 1];
        int s2 = ep[start + i + 2];
        int s3 = ep[start + i + 3];
        short8 r0 = *(const short8*)(in + (size_t)s0 * 32 + l * 8);
        short8 r1 = *(const short8*)(in + (size_t)s1 * 32 + l * 8);
        short8 r2 = *(const short8*)(in + (size_t)s2 * 32 + l * 8);
        short8 r3 = *(const short8*)(in + (size_t)s3 * 32 + l * 8);
#pragma unroll
        for (int j = 0; j < 8; j++) {
            acc[j] += b2f((ushort)r0[j]);
            acc[j] += b2f((ushort)r1[j]);
            acc[j] += b2f((ushort)r2[j]);
            acc[j] += b2f((ushort)r3[j]);
        }
    }
    for (; i < cnt; i++) {
        int s0 = ep[start + i];
        short8 r0 = *(const short8*)(in + (size_t)s0 * 32 + l * 8);
#pragma unroll
        for (int j = 0; j < 8; j++) acc[j] += b2f((ushort)r0[j]);
    }
    short8 o;
#pragma unroll
    for (int j = 0; j < 8; j++) o[j] = (short)f2b(dv * acc[j]);
    *(short8*)(out + (size_t)v * 32 + l * 8) = o;
}

// ---------------- GCN aggregation, fp8 rows (F=64) — R0 structure, plain loads -----------
template<bool OUT_BF16, bool BIAS, bool RELU>
__global__ __launch_bounds__(256) void agg_f8_k(const uchar* __restrict__ in, const int* __restrict__ rp,
                                                const int* __restrict__ indeg, const int* __restrict__ ep,
                                                const float* __restrict__ dinv,
                                                const float* __restrict__ bias, void* __restrict__ outp) {
    int g = threadIdx.x >> 3;          // 32 vertices per block
    int l = threadIdx.x & 7;           // 8 lanes x 8 fp8 = 64 B row
    int v = blockIdx.x * 32 + g;
    float dv = dinv[v];
    float acc[8] = {0, 0, 0, 0, 0, 0, 0, 0};
    f8x8_acc(*(const uint2*)(in + (size_t)v * 64 + l * 8), acc);   // self term
    int start = rp[v];
    int cnt   = indeg[v];
    int i = 0;
    for (; i + 8 <= cnt; i += 8) {     // 8 gathers in flight per lane
        int sx[8];
#pragma unroll
        for (int j = 0; j < 8; j++) sx[j] = ep[start + i + j];
        uint2 gx[8];
#pragma unroll
        for (int j = 0; j < 8; j++) gx[j] = *(const uint2*)(in + (size_t)sx[j] * 64 + l * 8);
#pragma unroll
        for (int j = 0; j < 8; j++) f8x8_acc(gx[j], acc);
    }
    for (; i + 4 <= cnt; i += 4) {
        int s0 = ep[start + i];
        int s1 = ep[start + i + 1];
        int s2 = ep[start + i + 2];
        int s3 = ep[start + i + 3];
        uint2 g0 = *(const uint2*)(in + (size_t)s0 * 64 + l * 8);
        uint2 g1 = *(const uint2*)(in + (size_t)s1 * 64 + l * 8);
        uint2 g2 = *(const uint2*)(in + (size_t)s2 * 64 + l * 8);
        uint2 g3 = *(const uint2*)(in + (size_t)s3 * 64 + l * 8);
        f8x8_acc(g0, acc); f8x8_acc(g1, acc); f8x8_acc(g2, acc); f8x8_acc(g3, acc);
    }
    for (; i < cnt; i++) {
        int s0 = ep[start + i];
        f8x8_acc(*(const uint2*)(in + (size_t)s0 * 64 + l * 8), acc);
    }
#pragma unroll
    for (int j = 0; j < 8; j++) {
        float x = dv * acc[j];
        if (BIAS) x += bias[l * 8 + j];
        if (RELU) x = fmaxf(x, 0.0f);
        acc[j] = x;
    }
    if (OUT_BF16) {
        short8 o;
#pragma unroll
        for (int j = 0; j < 8; j++) o[j] = (short)f2b(acc[j]);
        *(short8*)((ushort*)outp + (size_t)v * 64 + l * 8) = o;
    } else {
        *(uint2*)((uchar*)outp + (size_t)v * 64 + l * 8) = f8x8_pack(acc);
    }
}

// ---------------- fused GEMM1+GEMM2: h1=relu(xa@W1+b1) [LDS] ; h8a=(h1@W2)*dinv ----------
__global__ __launch_bounds__(256) void gemm12_k(const ushort* __restrict__ xa,
                                                const ushort* __restrict__ Wt1,
                                                const float* __restrict__ b1,
                                                const ushort* __restrict__ Wt2,
                                                const float* __restrict__ dinv,
                                                uchar* __restrict__ h8a) {
    __shared__ ushort s_h1[128][136];
    int w = threadIdx.x >> 6, lane = threadIdx.x & 63;
    int r16 = lane & 15, quad = lane >> 4, koff = quad * 8;
    size_t rows0 = (size_t)blockIdx.x * 128;

    short8 af1[2];
#pragma unroll
    for (int mt = 0; mt < 2; mt++)
        af1[mt] = *(const short8*)(xa + (rows0 + (w * 2 + mt) * 16 + r16) * 32 + koff);
#pragma unroll
    for (int nt = 0; nt < 8; nt++) {
        short8 bfr = *(const short8*)(Wt1 + (size_t)(nt * 16 + r16) * 32 + koff);
        f32x4 acc[2] = {{0.f,0.f,0.f,0.f},{0.f,0.f,0.f,0.f}};
        acc[0] = __builtin_amdgcn_mfma_f32_16x16x32_bf16(af1[0], bfr, acc[0], 0, 0, 0);
        acc[1] = __builtin_amdgcn_mfma_f32_16x16x32_bf16(af1[1], bfr, acc[1], 0, 0, 0);
        int col = nt * 16 + r16;
        float bc = b1[col];
#pragma unroll
        for (int mt = 0; mt < 2; mt++)
#pragma unroll
            for (int r = 0; r < 4; r++) {
                int rl = (w * 2 + mt) * 16 + quad * 4 + r;
                s_h1[rl][col] = f2b(fmaxf(acc[mt][r] + bc, 0.0f));
            }
    }
    __syncthreads();

    short8 af2[4][2];
#pragma unroll
    for (int kc = 0; kc < 4; kc++)
#pragma unroll
        for (int mt = 0; mt < 2; mt++)
            af2[kc][mt] = *(const short8*)&s_h1[(w * 2 + mt) * 16 + r16][kc * 32 + koff];
    float dvr[2][4];
#pragma unroll
    for (int mt = 0; mt < 2; mt++)
#pragma unroll
        for (int r = 0; r < 4; r++)
            dvr[mt][r] = dinv[rows0 + (w * 2 + mt) * 16 + quad * 4 + r];
#pragma unroll
    for (int nt = 0; nt < 4; nt++) {
        f32x4 acc[2] = {{0.f,0.f,0.f,0.f},{0.f,0.f,0.f,0.f}};
#pragma unroll
        for (int kc = 0; kc < 4; kc++) {
            short8 bfr = *(const short8*)(Wt2 + (size_t)(nt * 16 + r16) * 128 + kc * 32 + koff);
            acc[0] = __builtin_amdgcn_mfma_f32_16x16x32_bf16(af2[kc][0], bfr, acc[0], 0, 0, 0);
            acc[1] = __builtin_amdgcn_mfma_f32_16x16x32_bf16(af2[kc][1], bfr, acc[1], 0, 0, 0);
        }
#pragma unroll
        for (int mt = 0; mt < 2; mt++)
#pragma unroll
            for (int r = 0; r < 4; r++) {
                size_t row = rows0 + (w * 2 + mt) * 16 + quad * 4 + r;
                int col = nt * 16 + r16;
                h8a[row * 64 + col] = f2f8(acc[mt][r] * dvr[mt][r]);
            }
    }
}

// ---------------- fp8 GEMM via MFMA (K=64, N=64) ----------------
__global__ __launch_bounds__(256) void gemm_f8_k(const uchar* __restrict__ A8,
                                                 const uchar* __restrict__ Wt8,
                                                 const float* __restrict__ dinv,
                                                 uchar* __restrict__ out8) {
    int w = threadIdx.x >> 6, lane = threadIdx.x & 63;
    int r16 = lane & 15, koff = (lane >> 4) * 8;
    size_t rows0 = (size_t)blockIdx.x * 128;

    long af[2][2];
#pragma unroll
    for (int kc = 0; kc < 2; kc++)
#pragma unroll
        for (int mt = 0; mt < 2; mt++)
            af[kc][mt] = *(const long*)(A8 + (rows0 + (w * 2 + mt) * 16 + r16) * 64 + kc * 32 + koff);

    float dvr[2][4];
#pragma unroll
    for (int mt = 0; mt < 2; mt++)
#pragma unroll
        for (int r = 0; r < 4; r++)
            dvr[mt][r] = dinv[rows0 + (w * 2 + mt) * 16 + (lane >> 4) * 4 + r];

#pragma unroll
    for (int nt = 0; nt < 4; nt++) {
        f32x4 acc[2] = {{0.f,0.f,0.f,0.f},{0.f,0.f,0.f,0.f}};
#pragma unroll
        for (int kc = 0; kc < 2; kc++) {
            long b = *(const long*)(Wt8 + (size_t)(nt * 16 + r16) * 64 + kc * 32 + koff);
            acc[0] = __builtin_amdgcn_mfma_f32_16x16x32_fp8_fp8(af[kc][0], b, acc[0], 0, 0, 0);
            acc[1] = __builtin_amdgcn_mfma_f32_16x16x32_fp8_fp8(af[kc][1], b, acc[1], 0, 0, 0);
        }
#pragma unroll
        for (int mt = 0; mt < 2; mt++) {
#pragma unroll
            for (int r = 0; r < 4; r++) {
                size_t row = rows0 + (w * 2 + mt) * 16 + (lane >> 4) * 4 + r;
                int col = nt * 16 + (lane & 15);
                out8[row * 64 + col] = f2f8(acc[mt][r] * dvr[mt][r]);
            }
        }
    }
}

// ---------------- fused tail: hist + pool(q) + pool(c) + NTN + head, 1 block per pair ----
// 256 blocks x 1024 threads, ~117 KB LDS -> 1 block/CU. q,c tiles staged ONCE; e1/e2/hist
// stay in LDS; out[b] written directly (removes pool_hist dual loads + ntn launch).
__global__ __launch_bounds__(1024) void tail_k(const ushort* __restrict__ fin,
                                               const int* __restrict__ qsz, const int* __restrict__ csz,
                                               const float* __restrict__ attn_w,
                                               const float* __restrict__ A, const float* __restrict__ bw,
                                               const float* __restrict__ ntn_bias,
                                               const float* __restrict__ fc1w, const float* __restrict__ fc1b,
                                               const float* __restrict__ fc2w, const float* __restrict__ fc2b,
                                               float* __restrict__ out) {
    __shared__ ushort q_s[256][72];     // 36.9 KB
    __shared__ ushort c_s[256][72];     // 36.9 KB
    __shared__ ushort h[16 * 1024];     // 32 KB
    __shared__ int hp[16 * 64];         // 4 KB
    __shared__ float s_red[16 * 64];    // 4 KB
    __shared__ float s_sq[64], s_ctx[64], s_sig[256];
    __shared__ float smn[16], smx[16], s_sc[2];
    __shared__ float s_e1[64], s_e2[64];
    __shared__ float s_ntn[16], s_s[32], s_a[16];
    __shared__ int s_hist[16];

    int b = blockIdx.x;
    int t = threadIdx.x;
    int f = t & 63;                    // lane
    int w = t >> 6;                    // wave 0..15
    int r16 = f & 15, koff = (f >> 4) * 8;
    const ushort* qb = fin + (size_t)b * NN * 64;
    const ushort* cb = fin + (size_t)(NT + b * NN) * 64;

    // ---- stage both tiles once ----
#pragma unroll
    for (int it = 0; it < 2; it++) {
        int idx = it * 8192 + t * 8;
        int row = idx >> 6, f0 = idx & 63;
        *(short8*)&q_s[row][f0] = *(const short8*)(qb + idx);
        *(short8*)&c_s[row][f0] = *(const short8*)(cb + idx);
    }
    __syncthreads();

    // ---- hist: q fragments from LDS, one 16-row chunk per wave ----
    short8 a[2];
    {
        int qrow = w * 16 + r16;
        a[0] = *(const short8*)&q_s[qrow][koff];
        a[1] = *(const short8*)&q_s[qrow][32 + koff];
    }
    // pass A: min/max
    float mn = 1e30f, mx = -1e30f;
    for (int mt = 0; mt < 16; mt++) {
        int crow = mt * 16 + r16;
        short8 b0 = *(const short8*)&c_s[crow][koff];
        short8 b1 = *(const short8*)&c_s[crow][32 + koff];
        f32x4 acc = {0.0f, 0.0f, 0.0f, 0.0f};
        acc = __builtin_amdgcn_mfma_f32_16x16x32_bf16(a[0], b0, acc, 0, 0, 0);
        acc = __builtin_amdgcn_mfma_f32_16x16x32_bf16(a[1], b1, acc, 0, 0, 0);
        mn = fminf(mn, fminf(fminf(acc[0], acc[1]), fminf(acc[2], acc[3])));
        mx = fmaxf(mx, fmaxf(fmaxf(acc[0], acc[1]), fmaxf(acc[2], acc[3])));
    }
    for (int off = 32; off; off >>= 1) {
        mn = fminf(mn, __shfl_xor(mn, off, 64));
        mx = fmaxf(mx, __shfl_xor(mx, off, 64));
    }
    if (f == 0) { smn[w] = mn; smx[w] = mx; }
    __syncthreads();
    if (t == 0) {
        float m0 = smn[0], m1 = smx[0];
#pragma unroll
        for (int j = 1; j < 16; j++) {
            m0 = fminf(m0, smn[j]);
            m1 = fmaxf(m1, smx[j]);
        }
        s_sc[0] = m0;
        s_sc[1] = 16.0f / fmaxf(m1 - m0, 1e-12f);
    }
#pragma unroll
    for (int i = 0; i < 16; i++) h[i * 1024 + t] = 0;
    __syncthreads();
    float bmn = s_sc[0], bscale = s_sc[1];
    // pass B: recompute and bin (per-thread ushort slots; max 64 increments/slot)
    for (int mt = 0; mt < 16; mt++) {
        int crow = mt * 16 + r16;
        short8 b0 = *(const short8*)&c_s[crow][koff];
        short8 b1 = *(const short8*)&c_s[crow][32 + koff];
        f32x4 acc = {0.0f, 0.0f, 0.0f, 0.0f};
        acc = __builtin_amdgcn_mfma_f32_16x16x32_bf16(a[0], b0, acc, 0, 0, 0);
        acc = __builtin_amdgcn_mfma_f32_16x16x32_bf16(a[1], b1, acc, 0, 0, 0);
#pragma unroll
        for (int r = 0; r < 4; r++) {
            int bin = (int)floorf((acc[r] - bmn) * bscale);
            bin = min(max(bin, 0), 15);
            h[bin * 1024 + t] += 1;
        }
    }
    __syncthreads();
    {
        int bb = t >> 6, part = t & 63;
        int sum = 0;
#pragma unroll
        for (int j = 0; j < 16; j++) sum += (int)h[bb * 1024 + part * 16 + j];
        hp[bb * 64 + part] = sum;
    }
    __syncthreads();
    if (t < 16) {
        int s = 0;
#pragma unroll
        for (int j = 0; j < 64; j++) s += hp[t * 64 + j];
        s_hist[t] = s;
    }

    // ---- pool over q_s -> s_e1 ----
    {
        float psum = 0.0f;
#pragma unroll 8
        for (int i2 = 0; i2 < 16; i2++) psum += b2f(q_s[w * 16 + i2][f]);
        s_red[w * 64 + f] = psum;
        __syncthreads();
        if (w == 0) {
            float s = 0.0f;
#pragma unroll
            for (int j = 0; j < 16; j++) s += s_red[j * 64 + f];
            s_sq[f] = s;
            float acc = 0.0f;
            for (int k = 0; k < 64; k++) acc += s_sq[k] * attn_w[k * 64 + f];
            s_ctx[f] = tanhf(acc / (float)qsz[b]);
        }
        __syncthreads();
        if (t < 256) {
            float acc = 0.0f;
#pragma unroll 8
            for (int k = 0; k < 64; k++) acc += b2f(q_s[t][k]) * s_ctx[k];
            s_sig[t] = 1.0f / (1.0f + expf(-acc));
        }
        __syncthreads();
        float eacc = 0.0f;
#pragma unroll 8
        for (int i = 0; i < 16; i++) {
            int n = w * 16 + i;
            eacc += s_sig[n] * b2f(q_s[n][f]);
        }
        s_red[w * 64 + f] = eacc;
        __syncthreads();
        if (w == 0) {
            float s = 0.0f;
#pragma unroll
            for (int j = 0; j < 16; j++) s += s_red[j * 64 + f];
            s_e1[f] = s;
        }
    }
    __syncthreads();

    // ---- pool over c_s -> s_e2 ----
    {
        float psum = 0.0f;
#pragma unroll 8
        for (int i2 = 0; i2 < 16; i2++) psum += b2f(c_s[w * 16 + i2][f]);
        s_red[w * 64 + f] = psum;
        __syncthreads();
        if (w == 0) {
            float s = 0.0f;
#pragma unroll
            for (int j = 0; j < 16; j++) s += s_red[j * 64 + f];
            s_sq[f] = s;
            float acc = 0.0f;
            for (int k = 0; k < 64; k++) acc += s_sq[k] * attn_w[k * 64 + f];
            s_ctx[f] = tanhf(acc / (float)csz[b]);
        }
        __syncthreads();
        if (t < 256) {
            float acc = 0.0f;
#pragma unroll 8
            for (int k = 0; k < 64; k++) acc += b2f(c_s[t][k]) * s_ctx[k];
            s_sig[t] = 1.0f / (1.0f + expf(-acc));
        }
        __syncthreads();
        float eacc = 0.0f;
#pragma unroll 8
        for (int i = 0; i < 16; i++) {
            int n = w * 16 + i;
            eacc += s_sig[n] * b2f(c_s[n][f]);
        }
        s_red[w * 64 + f] = eacc;
        __syncthreads();
        if (w == 0) {
            float s = 0.0f;
#pragma unroll
            for (int j = 0; j < 16; j++) s += s_red[j * 64 + f];
            s_e2[f] = s;
        }
    }
    __syncthreads();

    // ---- NTN einsum: wave w handles slice tt = w; thread t = row (tt,i=f) of A ----
    {
        const float4* Ar = (const float4*)(A + (size_t)t * 64);
        float acc = 0.0f;
#pragma unroll
        for (int j = 0; j < 16; j++) {
            float4 a4 = Ar[j];
            acc += a4.x * s_e2[4 * j] + a4.y * s_e2[4 * j + 1]
                 + a4.z * s_e2[4 * j + 2] + a4.w * s_e2[4 * j + 3];
        }
        float p = s_e1[f] * acc;
        for (int off = 32; off; off >>= 1) p += __shfl_xor(p, off, 64);
        if (f == 0) s_ntn[w] = p;
    }
    __syncthreads();
    if (t < 16) {
        float acc = s_ntn[t] + ntn_bias[t];
        for (int k = 0; k < 64; k++) acc += s_e1[k] * bw[k * 16 + t];
        for (int k = 0; k < 64; k++) acc += s_e2[k] * bw[(64 + k) * 16 + t];
        s_s[t] = fmaxf(acc, 0.0f);
        s_s[16 + t] = (float)s_hist[t] * (1.0f / 65536.0f);
    }
    __syncthreads();
    if (t < 16) {
        float aa = fc1b[t];
        for (int k = 0; k < 32; k++) aa += s_s[k] * fc1w[k * 16 + t];
        s_a[t] = fmaxf(aa, 0.0f);
    }
    __syncthreads();
    if (t == 0) {
        float z = fc2b[0];
        for (int j = 0; j < 16; j++) z += s_a[j] * fc2w[j];
        float nz = -z;
        float sp = (nz > 20.0f) ? nz : log1pf(expf(nz));   // stable -log(sigmoid(z))
        out[b] = 0.5f * (float)(qsz[b] + csz[b]) * sp;
    }
}

// ---------------- launch ----------------
extern "C" void kernel_launch(void* const* d_in, const int* in_sizes, int n_in,
                              void* d_out, int out_size, void* d_ws, size_t ws_size,
                              hipStream_t stream) {
    const float* x_q    = (const float*)d_in[0];
    const int*   edge_q = (const int*)d_in[1];
    const float* x_c    = (const float*)d_in[2];
    const int*   edge_c = (const int*)d_in[3];
    const int*   qsz    = (const int*)d_in[4];
    const int*   csz    = (const int*)d_in[5];
    const float* W1 = (const float*)d_in[6];
    const float* b1 = (const float*)d_in[7];
    const float* W2 = (const float*)d_in[8];
    const float* b2 = (const float*)d_in[9];
    const float* W3 = (const float*)d_in[10];
    const float* b3 = (const float*)d_in[11];
    const float* attn_w  = (const float*)d_in[12];
    const float* ntn_a   = (const float*)d_in[13];
    const float* ntn_b   = (const float*)d_in[14];
    const float* ntn_bias= (const float*)d_in[15];
    const float* fc1w = (const float*)d_in[16];
    const float* fc1b = (const float*)d_in[17];
    const float* fc2w = (const float*)d_in[18];
    const float* fc2b = (const float*)d_in[19];
    float* out = (float*)d_out;

    char* w = (char*)d_ws;
    auto alloc = [&](size_t bytes) -> void* {
        void* p = (void*)w;
        w += (bytes + 255) & ~(size_t)255;
        return p;
    };
    int*    rp     = (int*)alloc((size_t)NT2 * 4);
    int*    indeg  = (int*)alloc((size_t)NT2 * 4);
    float*  dinv   = (float*)alloc((size_t)NT2 * 4);
    int*    gcount = (int*)alloc(NBUCK * 4);
    uint*   staged = (uint*)alloc((size_t)NBUCK * BCAP * 4);   // 10.5 MB packed
    int*    ep     = (int*)alloc((size_t)2 * NE * 4);           // 8.4 MB (src only)
    ushort* xb     = (ushort*)alloc((size_t)NT2 * 32 * 2);      // pre-scaled bf16 features
    ushort* xa     = (ushort*)alloc((size_t)NT2 * 32 * 2);      // agg1 output (bf16)
    uchar*  h8a    = (uchar*)alloc((size_t)NT2 * 64);           // fp8 64-d scratch
    uchar*  h8b    = (uchar*)alloc((size_t)NT2 * 64);           // fp8 64-d scratch
    ushort* fin    = (ushort*)alloc((size_t)NT2 * 64 * 2);      // qfin | cfin (bf16)
    ushort* Wt1    = (ushort*)alloc((size_t)DD * F1C * 2);
    ushort* Wt2    = (ushort*)alloc((size_t)F1C * F2C * 2);
    uchar*  Wt3f8  = (uchar*)alloc((size_t)F2C * F3C);

    // CSR build + weight cvt; p2 fuses the dinv feature pre-scale epilogue
    zero_k<<<1, 256, 0, stream>>>(gcount);
    p1cvt_k<<<512 + 32, 256, 0, stream>>>(edge_q, edge_c, staged, gcount,
                                          W1, W2, W3, Wt1, Wt2, Wt3f8);
    csr_p2_k<<<NBUCK, 256, 0, stream>>>(staged, gcount, rp, indeg, dinv, ep,
                                        x_q, x_c, xb);

    // GNN: standalone full-occupancy aggs (best-measured gather regime) + MFMA GEMMs
    agg_bf_k<<<NT2 / 64, 256, 0, stream>>>(xb, rp, indeg, ep, dinv, xa);
    gemm12_k<<<NT2 / 128, 256, 0, stream>>>(xa, Wt1, b1, Wt2, dinv, h8a);
    agg_f8_k<false, true, true><<<NT2 / 32, 256, 0, stream>>>(h8a, rp, indeg, ep, dinv, b2, h8b);
    gemm_f8_k<<<NT2 / 128, 256, 0, stream>>>(h8b, Wt3f8, dinv, h8a);
    agg_f8_k<true, true, false><<<NT2 / 32, 256, 0, stream>>>(h8a, rp, indeg, ep, dinv, b3, fin);

    // fused tail: hist + both pools + NTN + head in one kernel (1 block per pair)
    tail_k<<<BB, 1024, 0, stream>>>(fin, qsz, csz, attn_w, ntn_a, ntn_b, ntn_bias,
                                    fc1w, fc1b, fc2w, fc2b, out);
}